// Round 1
// 602.022 us; speedup vs baseline: 1.1309x; 1.1309x over previous
//
#include <hip/hip_runtime.h>

// QuietSTaR forward: embed->tanh MLP->lm_head, entropy gate, thought mixing,
// second lm_head GEMM, shifted CE loss.
// B=4 S=256 V=32000 H=1024 K=4 T=20; M=B*S=1024.
// Strategy: bf16 MFMA (16x16x32) for all 4 GEMMs; weights pre-transposed to
// (N,K) bf16; LDS tiles XOR-swizzled (no pad) for conflict-free ds_read_b128;
// entropy and LSE row-reductions fused into the big-GEMM epilogues (base
// logits never materialized; lse never re-reads logits).

#define V_SZ 32000
#define H_SZ 1024
#define S_SZ 256
#define B_SZ 4
#define M_SZ 1024
#define K_TH 4
#define T_TH 20
#define NTILE_V 250           // 32000/128
#define PARTS (NTILE_V * 2)   // per-row partials: 250 n-tiles x 2 wn-warps

typedef __bf16 bf16_t;
typedef __bf16 bf16x8 __attribute__((ext_vector_type(8)));
typedef __bf16 bf16x4 __attribute__((ext_vector_type(4)));
typedef float  f32x4  __attribute__((ext_vector_type(4)));

__device__ __forceinline__ float tanh_fast(float x) {
  x = fminf(fmaxf(x, -15.f), 15.f);
  float e = __expf(2.f * x);
  return (e - 1.f) / (e + 1.f);
}
__device__ __forceinline__ float sigmoid_f(float x) {
  return 1.f / (1.f + __expf(-x));
}

// ---------------- transpose + cast fp32 (R,C) -> bf16 (C,R) ----------------
__global__ void __launch_bounds__(256) transpose_cast_kernel(
    const float* __restrict__ in, bf16_t* __restrict__ out, int R, int C) {
  __shared__ float tile[32][33];
  const int tx = threadIdx.x & 31, ty = threadIdx.x >> 5;
  const int c0 = blockIdx.x << 5, r0 = blockIdx.y << 5;
  #pragma unroll
  for (int i = ty; i < 32; i += 8)
    tile[i][tx] = in[(size_t)(r0 + i) * C + c0 + tx];
  __syncthreads();
  #pragma unroll
  for (int i = ty; i < 32; i += 8)
    out[(size_t)(c0 + i) * R + r0 + tx] = (bf16_t)tile[tx][i];
}

// ---------------- embed row gather + cast to bf16 ----------------
__global__ void __launch_bounds__(256) gather_cast_kernel(
    const int* __restrict__ ids, const float* __restrict__ embed,
    bf16_t* __restrict__ X0) {
  const int i = blockIdx.x * 256 + threadIdx.x;   // over M*H/4
  const int m = i >> 8, c4 = (i & 255) << 2;      // H/4 = 256 chunks per row
  const float4 v = *(const float4*)(embed + (size_t)ids[m] * H_SZ + c4);
  bf16x4 o;
  o[0] = (bf16_t)v.x; o[1] = (bf16_t)v.y; o[2] = (bf16_t)v.z; o[3] = (bf16_t)v.w;
  *(bf16x4*)(X0 + (size_t)m * H_SZ + c4) = o;
}

// ---------------- bf16 MFMA GEMM: C(M,N) = A(M,K=1024) @ BT(N,K)^T ----------
// EPI 0: outF = acc
// EPI 1: v = tanh(acc + bias[n]); outF = v; outB = bf16(v)   (hidden)
// EPI 2: outF = tanh(acc)                                    (g)
// EPI 3: no logits write; entP[row][tn*2+wn] = (sum e^x, sum x e^x) over 64 cols
// EPI 4: outF = acc; lseP[row][tn*2+wn] = sum e^x over 64 cols
// LDS layout: row stride 32 elems (64B, no pad); 16B chunk c stored at
// c ^ ((row>>1)&3)  -> uniform bank-quad distribution on write and read.
template <int EPI>
__global__ void __launch_bounds__(256, 2) gemm_bt(
    const bf16_t* __restrict__ A, const bf16_t* __restrict__ BT,
    float* __restrict__ outF, bf16_t* __restrict__ outB,
    const float* __restrict__ bias, float2* __restrict__ entP,
    float* __restrict__ lseP, int mtiles, int ntiles, int N) {
  __shared__ __align__(16) bf16_t As[128 * 32];
  __shared__ __align__(16) bf16_t Bs[128 * 32];
  const int t = threadIdx.x;
  // swizzle: same-n-panel blocks share bid%8 (same XCD under round-robin)
  const int x = blockIdx.x & 7, y = blockIdx.x >> 3;
  const int tm = y % mtiles, tn = x + 8 * (y / mtiles);
  if (tn >= ntiles) return;
  const int m0 = tm * 128, n0 = tn * 128;
  const int lane = t & 63, wv = t >> 6, wm = wv >> 1, wn = wv & 1;
  const int col = lane & 15, qd = lane >> 4;
  const int ldr = t >> 2, ldch = t & 3;           // staging row / 16B chunk
  // swizzled staging destinations (row>>1 has same low bits for row and row+64)
  const int st0 = ldr * 32 + ((ldch ^ ((ldr >> 1) & 3)) << 3);
  const int st1 = (ldr + 64) * 32 + ((ldch ^ ((ldr >> 1) & 3)) << 3);
  // swizzled fragment-read offsets (hoisted; constant over K)
  int offA[4], offB[4];
  #pragma unroll
  for (int i = 0; i < 4; ++i) {
    const int ra = wm * 64 + i * 16 + col;
    offA[i] = ra * 32 + ((qd ^ ((ra >> 1) & 3)) << 3);
    const int rb = wn * 64 + i * 16 + col;
    offB[i] = rb * 32 + ((qd ^ ((rb >> 1) & 3)) << 3);
  }
  f32x4 acc[4][4] = {};
  for (int kb = 0; kb < 1024; kb += 32) {
    {
      uint4 a0 = *(const uint4*)(A  + (size_t)(m0 + ldr) * 1024 + kb + ldch * 8);
      uint4 b0 = *(const uint4*)(BT + (size_t)(n0 + ldr) * 1024 + kb + ldch * 8);
      uint4 a1 = *(const uint4*)(A  + (size_t)(m0 + ldr + 64) * 1024 + kb + ldch * 8);
      uint4 b1 = *(const uint4*)(BT + (size_t)(n0 + ldr + 64) * 1024 + kb + ldch * 8);
      *(uint4*)(As + st0) = a0;
      *(uint4*)(Bs + st0) = b0;
      *(uint4*)(As + st1) = a1;
      *(uint4*)(Bs + st1) = b1;
    }
    __syncthreads();
    bf16x8 af[4], bg[4];
    #pragma unroll
    for (int mi = 0; mi < 4; ++mi) af[mi] = *(const bf16x8*)(As + offA[mi]);
    #pragma unroll
    for (int ni = 0; ni < 4; ++ni) bg[ni] = *(const bf16x8*)(Bs + offB[ni]);
    #pragma unroll
    for (int mi = 0; mi < 4; ++mi)
      #pragma unroll
      for (int ni = 0; ni < 4; ++ni)
        acc[mi][ni] = __builtin_amdgcn_mfma_f32_16x16x32_bf16(
            af[mi], bg[ni], acc[mi][ni], 0, 0, 0);
    __syncthreads();
  }

  if (EPI == 3 || EPI == 4) {
    // row r of this thread: m0 + wm*64 + mi*16 + qd*4 + rr ; cols: 4 (ni)
    float z[16], s[16];
    #pragma unroll
    for (int mi = 0; mi < 4; ++mi) {
      #pragma unroll
      for (int rr = 0; rr < 4; ++rr) {
        float zz = 0.f, ss = 0.f;
        #pragma unroll
        for (int ni = 0; ni < 4; ++ni) {
          const float xv = acc[mi][ni][rr];
          const float e = __expf(xv);   // logits bounded (|x| < ~6): no max needed
          zz += e;
          if (EPI == 3) ss += xv * e;
          if (EPI == 4) {
            const size_t o = (size_t)(m0 + wm * 64 + mi * 16 + qd * 4 + rr) * N
                           + (n0 + wn * 64 + ni * 16 + col);
            outF[o] = xv;
          }
        }
        z[mi * 4 + rr] = zz;
        s[mi * 4 + rr] = ss;
      }
    }
    // butterfly over the 16 col-lanes (same qd group)
    #pragma unroll
    for (int d = 1; d < 16; d <<= 1) {
      #pragma unroll
      for (int i = 0; i < 16; ++i) {
        z[i] += __shfl_xor(z[i], d);
        if (EPI == 3) s[i] += __shfl_xor(s[i], d);
      }
    }
    if (col == 0) {
      #pragma unroll
      for (int i = 0; i < 16; ++i) {
        const int row = m0 + wm * 64 + (i >> 2) * 16 + qd * 4 + (i & 3);
        if (EPI == 3)
          entP[(size_t)row * PARTS + tn * 2 + wn] = make_float2(z[i], s[i]);
        else
          lseP[(size_t)row * PARTS + tn * 2 + wn] = z[i];
      }
    }
    return;
  }

  // epilogue EPI 0/1/2: D row = qd*4 + r, col = lane&15
  #pragma unroll
  for (int mi = 0; mi < 4; ++mi) {
    #pragma unroll
    for (int ni = 0; ni < 4; ++ni) {
      const int gm = m0 + wm * 64 + mi * 16 + qd * 4;
      const int gn = n0 + wn * 64 + ni * 16 + col;
      #pragma unroll
      for (int r = 0; r < 4; ++r) {
        const size_t o = (size_t)(gm + r) * N + gn;
        float v = acc[mi][ni][r];
        if (EPI == 1) {
          v = tanh_fast(v + bias[gn]);
          outF[o] = v;
          outB[o] = (bf16_t)v;
        } else if (EPI == 2) {
          outF[o] = tanh_fast(v);
        } else {
          outF[o] = v;
        }
      }
    }
  }
}

// ------- merge entropy partials over 500 tiles/row, 4 batch rows -> inject --
__global__ void __launch_bounds__(256) ent_inject_kernel(
    const float2* __restrict__ entP, int* __restrict__ inject) {
  const int s = blockIdx.x, t = threadIdx.x;
  const int b = t >> 6, lane = t & 63;   // wave b handles batch-row b
  const int row = b * S_SZ + s;
  float z = 0.f, sv = 0.f;
  for (int i = lane; i < PARTS; i += 64) {
    const float2 p = entP[(size_t)row * PARTS + i];
    z += p.x; sv += p.y;
  }
  #pragma unroll
  for (int d = 1; d < 64; d <<= 1) {
    z += __shfl_xor(z, d);
    sv += __shfl_xor(sv, d);
  }
  __shared__ float se[4];
  if (lane == 0) se[b] = __logf(z) - sv / z;   // entropy (natural log)
  __syncthreads();
  if (t == 0) {
    const float e = 0.25f * (se[0] + se[1] + se[2] + se[3]);
    inject[s] = (e * (1.0f / 10.373491f) > 0.6f) && (s < S_SZ - 1) ? 1 : 0;
  }
}

// ---------------- merge LSE partials: lse[row] = log(sum Z) ----------------
__global__ void __launch_bounds__(256) lse_merge_kernel(
    const float* __restrict__ lseP, float* __restrict__ lse) {
  const int t = threadIdx.x, w = t >> 6, lane = t & 63;
  const int row = blockIdx.x * 4 + w;
  float z = 0.f;
  for (int i = lane; i < PARTS; i += 64) z += lseP[(size_t)row * PARTS + i];
  #pragma unroll
  for (int d = 1; d < 64; d <<= 1) z += __shfl_xor(z, d);
  if (lane == 0) lse[row] = __logf(z);
}

// ---------------- tmean[m][k][h] = mean_t tanh(g + te_k + tp_t) -------------
__global__ void __launch_bounds__(256) thoughts_kernel(
    const float* __restrict__ g, const float* __restrict__ th_emb,
    const float* __restrict__ tpos, float* __restrict__ tmean) {
  const int idx = blockIdx.x * 256 + threadIdx.x;  // over M*K*H
  const int h = idx & (H_SZ - 1);
  const int mk = idx >> 10;
  const int kk = mk & (K_TH - 1);
  const int m = mk >> 2;
  const float base = g[(size_t)m * H_SZ + h] + th_emb[kk * H_SZ + h];
  float s = 0.f;
  #pragma unroll
  for (int tt = 0; tt < T_TH; ++tt) s += tanh_fast(base + tpos[tt * H_SZ + h]);
  tmean[idx] = s * (1.f / T_TH);
}

// ---------------- scorer + softmax mix + gate + enhanced (bf16) -------------
__device__ __forceinline__ float block_sum(float v, float* red, int t) {
  red[t] = v;
  __syncthreads();
  for (int off = 128; off > 0; off >>= 1) {
    if (t < off) red[t] += red[t + off];
    __syncthreads();
  }
  const float r = red[0];
  __syncthreads();
  return r;
}

__global__ void __launch_bounds__(256) mix_kernel(
    const float* __restrict__ hidden, const float* __restrict__ tmean,
    const float* __restrict__ w_score, const float* __restrict__ w_gate,
    const int* __restrict__ inject, bf16_t* __restrict__ enhB) {
  const int m = blockIdx.x, t = threadIdx.x, s = m & (S_SZ - 1);
  __shared__ float red[256];
  float hv[4], ws1[4], ws2[4], wg1[4], wg2[4], tmv[4][4];
  #pragma unroll
  for (int j = 0; j < 4; ++j) {
    const int h = t + 256 * j;
    hv[j]  = hidden[(size_t)m * H_SZ + h];
    ws1[j] = w_score[h];      ws2[j] = w_score[H_SZ + h];
    wg1[j] = w_gate[h];       wg2[j] = w_gate[H_SZ + h];
    #pragma unroll
    for (int k = 0; k < 4; ++k) tmv[k][j] = tmean[(size_t)(m * 4 + k) * H_SZ + h];
  }
  float ph = 0.f, pg = 0.f;
  #pragma unroll
  for (int j = 0; j < 4; ++j) { ph += hv[j] * ws1[j]; pg += hv[j] * wg1[j]; }
  const float sh = block_sum(ph, red, t);
  const float gh = block_sum(pg, red, t);
  float comp[4];
  #pragma unroll
  for (int k = 0; k < 4; ++k) {
    float pc = 0.f;
    #pragma unroll
    for (int j = 0; j < 4; ++j) pc += tmv[k][j] * ws2[j];
    const float ck = block_sum(pc, red, t);
    comp[k] = sigmoid_f(sh + ck);
  }
  const float ma = fmaxf(fmaxf(comp[0], comp[1]), fmaxf(comp[2], comp[3]));
  float al[4], asum = 0.f;
  #pragma unroll
  for (int k = 0; k < 4; ++k) { al[k] = __expf(comp[k] - ma); asum += al[k]; }
  const float inv = 1.f / asum;
  float mx[4];
  #pragma unroll
  for (int j = 0; j < 4; ++j) {
    mx[j] = 0.f;
    #pragma unroll
    for (int k = 0; k < 4; ++k) mx[j] += al[k] * inv * tmv[k][j];
  }
  float pm = 0.f;
  #pragma unroll
  for (int j = 0; j < 4; ++j) pm += mx[j] * wg2[j];
  const float gm = block_sum(pm, red, t);
  const float gate = sigmoid_f(gh + gm);
  const int inj = inject[s];
  #pragma unroll
  for (int j = 0; j < 4; ++j) {
    const float e = inj ? (gate * mx[j] + (1.f - gate) * hv[j]) : hv[j];
    enhB[(size_t)m * H_SZ + t + 256 * j] = (bf16_t)e;
  }
}

// ---------------- shifted CE loss ----------------
__global__ void __launch_bounds__(256) loss_kernel(
    const float* __restrict__ logits, const float* __restrict__ lse,
    const int* __restrict__ labels, float* __restrict__ out_loss) {
  const int t = threadIdx.x;
  float acc = 0.f;
  for (int i = t; i < (S_SZ - 1) * B_SZ; i += 256) {
    const int b = i / (S_SZ - 1), s2 = i % (S_SZ - 1);
    const int m = b * S_SZ + s2;
    const int lab = labels[m + 1];
    acc += lse[m] - logits[(size_t)m * V_SZ + lab];
  }
  __shared__ float red[256];
  red[t] = acc;
  __syncthreads();
  for (int off = 128; off > 0; off >>= 1) {
    if (t < off) red[t] += red[t + off];
    __syncthreads();
  }
  if (t == 0) out_loss[0] = red[0] / (float)((S_SZ - 1) * B_SZ);
}

extern "C" void kernel_launch(void* const* d_in, const int* in_sizes, int n_in,
                              void* d_out, int out_size, void* d_ws, size_t ws_size,
                              hipStream_t stream) {
  const int*   ids    = (const int*)  d_in[0];
  const int*   labels = (const int*)  d_in[1];
  const float* embed  = (const float*)d_in[2];
  const float* W1     = (const float*)d_in[3];
  const float* b1     = (const float*)d_in[4];
  const float* lm     = (const float*)d_in[5];
  const float* Wg     = (const float*)d_in[6];
  const float* thE    = (const float*)d_in[7];
  const float* tpos   = (const float*)d_in[8];
  const float* wsc    = (const float*)d_in[9];
  const float* wgt    = (const float*)d_in[10];
  float* out = (float*)d_out;

  // workspace carve (~98 MB)
  char* p = (char*)d_ws;
  auto carve = [&p](size_t bytes) {
    char* r = p;
    p += (bytes + 255) & ~(size_t)255;
    return r;
  };
  bf16_t* lmT   = (bf16_t*)carve((size_t)V_SZ * H_SZ * sizeof(bf16_t));  // (V,H)
  bf16_t* W1T   = (bf16_t*)carve((size_t)H_SZ * H_SZ * sizeof(bf16_t));
  bf16_t* WgT   = (bf16_t*)carve((size_t)H_SZ * H_SZ * sizeof(bf16_t));
  bf16_t* X0    = (bf16_t*)carve((size_t)M_SZ * H_SZ * sizeof(bf16_t));
  bf16_t* hidB  = (bf16_t*)carve((size_t)M_SZ * H_SZ * sizeof(bf16_t));
  bf16_t* enhB  = (bf16_t*)carve((size_t)M_SZ * H_SZ * sizeof(bf16_t));
  float*  hidF  = (float*) carve((size_t)M_SZ * H_SZ * sizeof(float));
  float*  gF    = (float*) carve((size_t)M_SZ * H_SZ * sizeof(float));
  float*  tmean = (float*) carve((size_t)M_SZ * K_TH * H_SZ * sizeof(float));
  float*  lse   = (float*) carve(M_SZ * sizeof(float));
  int*    inj   = (int*)   carve(S_SZ * sizeof(int));
  // entropy/LSE partials alias tmean (disjoint lifetimes):
  //   entP written by gemm<3>, read by ent_inject BEFORE thoughts writes tmean;
  //   lseP written by gemm<4> AFTER mix has consumed tmean.
  float2* entP = (float2*)tmean;                    // 1024*500*8B = 4 MB
  float*  lseP = (float*)tmean;                     // 1024*500*4B = 2 MB

  // weight prep
  transpose_cast_kernel<<<dim3(V_SZ / 32, H_SZ / 32), 256, 0, stream>>>(lm, lmT, H_SZ, V_SZ);
  transpose_cast_kernel<<<dim3(H_SZ / 32, H_SZ / 32), 256, 0, stream>>>(W1, W1T, H_SZ, H_SZ);
  transpose_cast_kernel<<<dim3(H_SZ / 32, H_SZ / 32), 256, 0, stream>>>(Wg, WgT, H_SZ, H_SZ);
  gather_cast_kernel<<<M_SZ * H_SZ / 4 / 256, 256, 0, stream>>>(ids, embed, X0);

  // base model
  gemm_bt<1><<<64, 256, 0, stream>>>(X0, W1T, hidF, hidB, b1, nullptr, nullptr, 8, 8, H_SZ);
  gemm_bt<2><<<64, 256, 0, stream>>>(hidB, WgT, gF, nullptr, nullptr, nullptr, nullptr, 8, 8, H_SZ);
  // base logits -> fused entropy partials (logits never materialized)
  gemm_bt<3><<<2048, 256, 0, stream>>>(hidB, lmT, nullptr, nullptr, nullptr, entP, nullptr, 8, NTILE_V, V_SZ);
  ent_inject_kernel<<<S_SZ, 256, 0, stream>>>(entP, inj);

  // thoughts + mix
  thoughts_kernel<<<M_SZ * K_TH * H_SZ / 256, 256, 0, stream>>>(gF, thE, tpos, tmean);
  mix_kernel<<<M_SZ, 256, 0, stream>>>(hidF, tmean, wsc, wgt, inj, enhB);

  // final logits (+ fused LSE partials) + loss
  gemm_bt<4><<<2048, 256, 0, stream>>>(enhB, lmT, out, nullptr, nullptr, nullptr, lseP, 8, NTILE_V, V_SZ);
  lse_merge_kernel<<<M_SZ / 4, 256, 0, stream>>>(lseP, lse);
  loss_kernel<<<1, 256, 0, stream>>>(out, lse, labels, out + (size_t)M_SZ * V_SZ);
}